// Round 4
// baseline (254.387 us; speedup 1.0000x reference)
//
#include <hip/hip_runtime.h>
#include <cstdint>

#define CN (384*1024)          // 393216
#define BCN (16*CN)            // 6291456
#define EPS 1e-5f

// workspace layout (bytes)
#define WPT_OFF   0u           // f32[384][384] = 589824
#define WQB_OFF   589824u      // bf16-as-u16[385][384] = 295680 (row 384 = zeros), ends 885504
#define QINV_OFF  1179648u
#define QOFF_OFF  (QINV_OFF + 1536u)
#define PINV_OFF  (QINV_OFF + 3072u)
#define POFF_OFF  (QINV_OFF + 4608u)
#define C0_OFF    (QINV_OFF + 6144u)
#define XM_OFF    2097152u     // u64[4][16][16][384] n-packed spikes, 3145728 B (ends 5242880)
#define XMT_OFF   5242880u     // u64[4][16][1024][6] c-packed spikes, 3145728 B (ends 8388608)
#define MST_OFF   XM_OFF       // masked q-spikes, c-packed; reuses xm (dead after k1b)

// ---------------- K0a: transposes: wp -> f32 wpT, wq -> bf16 wqb (+ zero row) ------
__global__ __launch_bounds__(256) void k0_transpose(const float* __restrict__ wq,
                                                    const float* __restrict__ wp,
                                                    char* __restrict__ ws) {
    int bid = blockIdx.x;
    if (bid < 576) {
        int i = bid * 256 + threadIdx.x;             // 0..147455
        int c = i / 384, o = i % 384;
        ((float*)(ws + WPT_OFF))[c * 384 + o] = wp[o * 384 + c];
    } else {
        int j = (bid - 576) * 256 + threadIdx.x;     // 0..147967
        if (j >= 147840) return;                     // 385*384
        int r = j / 384, o = j % 384;
        unsigned short v = 0;
        if (r < 384) {
            unsigned u = __float_as_uint(wq[o * 384 + r]);
            v = (unsigned short)((u + 0x7fffu + ((u >> 16) & 1u)) >> 16);  // rne bf16
        }
        ((unsigned short*)(ws + WQB_OFF))[j] = v;
    }
}

// ---------------- K0b: BN constants ----------------
__global__ void k0_consts(const float* __restrict__ qg, const float* __restrict__ qb,
                          const float* __restrict__ qm, const float* __restrict__ qv,
                          const float* __restrict__ pg, const float* __restrict__ pb,
                          const float* __restrict__ pm, const float* __restrict__ pv,
                          const float* __restrict__ bp, char* __restrict__ ws) {
    int i = threadIdx.x;                         // 384 threads
    float qi = qg[i] / sqrtf(qv[i] + EPS);
    ((float*)(ws + QINV_OFF))[i] = qi;
    ((float*)(ws + QOFF_OFF))[i] = qb[i] - qm[i] * qi;
    float pi = pg[i] / sqrtf(pv[i] + EPS);
    float po = pb[i] - pm[i] * pi;
    ((float*)(ws + PINV_OFF))[i] = pi;
    ((float*)(ws + POFF_OFF))[i] = po;
    ((float*)(ws + C0_OFF))[i] = bp[i] * pi + po;   // output value when GEMM2 input is all-zero
}

// ---------------- K1: shortcut LIF -> n-packed spike bitmasks ----------------
__global__ __launch_bounds__(256) void k1_lif(const float* __restrict__ x,
                                              unsigned long long* __restrict__ xm) {
    int wid  = (blockIdx.x * 256 + threadIdx.x) >> 6;   // 0..98303
    int lane = threadIdx.x & 63;
    int c = wid % 384;
    int g = (wid / 384) & 15;
    int b = wid / (384 * 16);
    const float* xp = x + (size_t)b * CN + (size_t)c * 1024 + g * 64 + lane;
    float v = 0.f;
    #pragma unroll
    for (int t = 0; t < 4; ++t) {
        float xv = xp[(size_t)t * BCN];
        float h = v + (xv - v) * 0.5f;                  // v + (x - v)/tau, tau = 2
        bool s = (h >= 1.0f);
        unsigned long long m = __ballot(s);
        v = s ? 0.f : h;
        if (lane == 0) xm[(((size_t)t * 16 + b) * 16 + g) * 384 + c] = m;
    }
}

// ---------------- K1b: 64x64 bit transpose: n-packed -> c-packed ----------------
__global__ __launch_bounds__(256) void k1b_transpose(const unsigned long long* __restrict__ xm,
                                                     unsigned long long* __restrict__ xmT) {
    int wid  = (blockIdx.x * 256 + threadIdx.x) >> 6;   // 0..6143
    int lane = threadIdx.x & 63;
    int cg = wid % 6;
    int g  = (wid / 6) % 16;
    int tb = wid / 96;                                  // t*16 + b
    unsigned long long W = xm[((size_t)tb * 16 + g) * 384 + cg * 64 + lane];
    unsigned long long T = 0ull;
    #pragma unroll
    for (int k = 0; k < 64; ++k) {
        unsigned long long bk = __ballot((W >> k) & 1ull);  // bit c = spike(c, n=g*64+k)
        if (lane == k) T = bk;
    }
    xmT[((size_t)tb * 1024 + g * 64 + lane) * 6 + cg] = T;
}

// ---------------- K2: 8-stream interleaved gather GEMM1 + BN + q-LIF + attn mask ---
// block = (b, 16-n tile); 384 threads; thread owns output channel o = tid.
// Streams: 2 n-columns x 4 timesteps, each with private mask word + accumulator.
// Rounds issue 8 unconditional bf16 row loads (empty streams hit zero row 384)
// -> 8 loads in flight per wave. Mask words double-buffered across the cg loop.
__global__ __launch_bounds__(384) void k2_qpath(const unsigned short* __restrict__ wqb,
                                                const float* __restrict__ qinv_,
                                                const float* __restrict__ qoff_,
                                                const unsigned long long* __restrict__ xmT,
                                                const unsigned char* __restrict__ ak,
                                                const unsigned char* __restrict__ av,
                                                unsigned long long* __restrict__ msT) {
    const int tid  = threadIdx.x;                // output channel o
    const int lane = tid & 63;
    const int wgrp = tid >> 6;                   // o-group 0..5
    const int bid  = blockIdx.x;
    const int nt   = bid & 63;                   // 16-wide n-tile
    const int b    = bid >> 6;
    const float qi = qinv_[tid], qo = qoff_[tid];

    for (int np = 0; np < 8; ++np) {
        const int n0 = nt * 16 + np * 2;         // two n's: n0, n0+1
        float acc[8] = {0.f,0.f,0.f,0.f,0.f,0.f,0.f,0.f};
        unsigned long long cur[8], nxt[8];
        #pragma unroll
        for (int u = 0; u < 8; ++u) {            // u = p*4 + t
            int p = u >> 2, t = u & 3;
            cur[u] = xmT[((size_t)(t * 16 + b) * 1024 + n0 + p) * 6 + 0];
        }
        for (int cg = 0; cg < 6; ++cg) {
            if (cg < 5) {
                #pragma unroll
                for (int u = 0; u < 8; ++u) {
                    int p = u >> 2, t = u & 3;
                    nxt[u] = xmT[((size_t)(t * 16 + b) * 1024 + n0 + p) * 6 + cg + 1];
                }
            }
            unsigned long long s[8];
            #pragma unroll
            for (int u = 0; u < 8; ++u) {        // masks are block-uniform -> scalarize
                unsigned lo = __builtin_amdgcn_readfirstlane((unsigned)(cur[u] & 0xffffffffull));
                unsigned hi = __builtin_amdgcn_readfirstlane((unsigned)(cur[u] >> 32));
                s[u] = ((unsigned long long)hi << 32) | lo;
            }
            while (s[0]|s[1]|s[2]|s[3]|s[4]|s[5]|s[6]|s[7]) {
                int idx[8];
                #pragma unroll
                for (int u = 0; u < 8; ++u) {
                    int j = __builtin_ctzll(s[u] | 1ull);
                    idx[u] = s[u] ? (cg * 64 + j) : 384;   // 384 = zero dummy row
                    s[u] &= s[u] - 1;
                }
                float wv[8];
                #pragma unroll
                for (int u = 0; u < 8; ++u)
                    wv[u] = __uint_as_float((unsigned)wqb[idx[u] * 384 + tid] << 16);
                #pragma unroll
                for (int u = 0; u < 8; ++u) acc[u] += wv[u];
            }
            #pragma unroll
            for (int u = 0; u < 8; ++u) cur[u] = nxt[u];
        }
        // BN + LIF + attn-mask epilogue for the two n's
        #pragma unroll
        for (int p = 0; p < 2; ++p) {
            float v = 0.f;
            #pragma unroll
            for (int t = 0; t < 4; ++t) {
                float qbn = acc[p * 4 + t] * qi + qo;
                float h = 0.5f * (v + qbn);      // v + (q - v)/2
                bool sp = (h >= 1.0f);
                v = sp ? 0.f : h;
                if (sp) {                         // rare: attn-mask lookup only on q-spike
                    size_t ix = ((size_t)((t * 16 + b) * 384 + tid) << 10) + (n0 + p);
                    sp = (ak[ix] != 0) && (av[ix] != 0);
                }
                unsigned long long bw = __ballot(sp);
                if (lane == 0)
                    msT[((size_t)(t * 16 + b) * 1024 + n0 + p) * 6 + wgrp] = bw;
            }
        }
    }
}

// ---------------- K3: proj GEMM2 + bias + BN (gather-based, atomic-free) ----------
__global__ __launch_bounds__(384) void k3_proj(const float* __restrict__ wpT,
                                               const float* __restrict__ pinv_,
                                               const float* __restrict__ poff_,
                                               const float* __restrict__ bp,
                                               const float* __restrict__ c0,
                                               const unsigned long long* __restrict__ msT,
                                               float* __restrict__ out) {
    __shared__ unsigned int wflag[6];
    const int tid = threadIdx.x;
    const int bid = blockIdx.x;
    const int g = bid & 15, b = (bid >> 4) & 15, t = bid >> 8;
    const unsigned long long* mbase = msT + ((size_t)(t * 16 + b) * 1024 + g * 64) * 6;
    unsigned long long m = mbase[tid];           // 384 words: n-local = tid/6, cg = tid%6
    unsigned long long anyb = __ballot(m != 0ull);
    if ((tid & 63) == 0) wflag[tid >> 6] = (anyb != 0ull) ? 1u : 0u;
    __syncthreads();
    unsigned int any = wflag[0] | wflag[1] | wflag[2] | wflag[3] | wflag[4] | wflag[5];
    size_t obase = (size_t)(t * 16 + b) * 384;

    if (!any) {
        // all-zero GEMM2 input: out = bp*inv + off, coalesced float4 stores
        #pragma unroll
        for (int k = 0; k < 16; ++k) {
            int i = tid + k * 384;               // 6144 float4 units in the (384o x 64n) tile
            int o = i >> 4, n4 = i & 15;
            float vv = c0[o];
            float4* dst = (float4*)out + (obase + o) * 256 + g * 16 + n4;
            *dst = make_float4(vv, vv, vv, vv);
        }
        return;
    }
    // slow path (never taken on this input): per-n VGPR gather
    float pi = pinv_[tid], po = poff_[tid], bb = bp[tid];
    for (int nl = 0; nl < 64; ++nl) {
        float acc = 0.f;
        #pragma unroll
        for (int cg = 0; cg < 6; ++cg) {
            unsigned long long mm = mbase[nl * 6 + cg];
            while (mm) {
                int j = __builtin_ctzll(mm);
                mm &= mm - 1;
                acc += wpT[(size_t)(cg * 64 + j) * 384 + tid];
            }
        }
        out[(obase + tid) * 1024 + g * 64 + nl] = (acc + bb) * pi + po;
    }
}

extern "C" void kernel_launch(void* const* d_in, const int* in_sizes, int n_in,
                              void* d_out, int out_size, void* d_ws, size_t ws_size,
                              hipStream_t stream) {
    const float* x  = (const float*)d_in[0];
    const unsigned char* ak = (const unsigned char*)d_in[1];
    const unsigned char* av = (const unsigned char*)d_in[2];
    const float* wq = (const float*)d_in[3];
    const float* qg = (const float*)d_in[4];
    const float* qb = (const float*)d_in[5];
    const float* qm = (const float*)d_in[6];
    const float* qv = (const float*)d_in[7];
    const float* wp = (const float*)d_in[8];
    const float* bp = (const float*)d_in[9];
    const float* pg = (const float*)d_in[10];
    const float* pb = (const float*)d_in[11];
    const float* pm = (const float*)d_in[12];
    const float* pv = (const float*)d_in[13];
    char* ws = (char*)d_ws;
    float* out = (float*)d_out;

    hipLaunchKernelGGL(k0_transpose, dim3(1154), dim3(256), 0, stream, wq, wp, ws);
    hipLaunchKernelGGL(k0_consts, dim3(1), dim3(384), 0, stream,
                       qg, qb, qm, qv, pg, pb, pm, pv, bp, ws);
    hipLaunchKernelGGL(k1_lif, dim3(24576), dim3(256), 0, stream,
                       x, (unsigned long long*)(ws + XM_OFF));
    hipLaunchKernelGGL(k1b_transpose, dim3(1536), dim3(256), 0, stream,
                       (const unsigned long long*)(ws + XM_OFF),
                       (unsigned long long*)(ws + XMT_OFF));
    hipLaunchKernelGGL(k2_qpath, dim3(1024), dim3(384), 0, stream,
                       (const unsigned short*)(ws + WQB_OFF),
                       (const float*)(ws + QINV_OFF), (const float*)(ws + QOFF_OFF),
                       (const unsigned long long*)(ws + XMT_OFF), ak, av,
                       (unsigned long long*)(ws + MST_OFF));
    hipLaunchKernelGGL(k3_proj, dim3(1024), dim3(384), 0, stream,
                       (const float*)(ws + WPT_OFF), (const float*)(ws + PINV_OFF),
                       (const float*)(ws + POFF_OFF), bp, (const float*)(ws + C0_OFF),
                       (const unsigned long long*)(ws + MST_OFF), out);
}

// Round 5
// 142.110 us; speedup vs baseline: 1.7901x; 1.7901x over previous
//
#include <hip/hip_runtime.h>
#include <cstdint>

#define CN (384*1024)          // 393216
#define BCN (16*CN)            // 6291456
#define EPS 1e-5f
#define LCAP 24                // index-list capacity per (t,b,n) column

// workspace layout (bytes)
#define WPT_OFF   0u           // f32[384][384] = 589824
#define WQB_OFF   589824u      // bf16-as-u16[385][384] = 295680 (row 384 = zeros), ends 885504
#define QINV_OFF  1179648u
#define QOFF_OFF  (QINV_OFF + 1536u)
#define PINV_OFF  (QINV_OFF + 3072u)
#define POFF_OFF  (QINV_OFF + 4608u)
#define C0_OFF    (QINV_OFF + 6144u)
#define LCNT_OFF  1187840u     // u8[65536], ends 1253376
#define LISTS_OFF 2097152u     // u16[65536][24] = 3145728, ends 5242880
#define XMT_OFF   5242880u     // u64[4][16][1024][6] c-packed spikes, ends 8388608
#define XM_OFF    8388608u     // u64[4][16][16][384] n-packed spikes, ends 11534336
#define MST_OFF   XM_OFF       // masked q-spikes, c-packed; reuses xm (dead after k1b)

// ---------------- K0a: transposes: wp -> f32 wpT, wq -> bf16 wqb (+ zero row) ------
__global__ __launch_bounds__(256) void k0_transpose(const float* __restrict__ wq,
                                                    const float* __restrict__ wp,
                                                    char* __restrict__ ws) {
    int bid = blockIdx.x;
    if (bid < 576) {
        int i = bid * 256 + threadIdx.x;             // 0..147455
        int c = i / 384, o = i % 384;
        ((float*)(ws + WPT_OFF))[c * 384 + o] = wp[o * 384 + c];
    } else {
        int j = (bid - 576) * 256 + threadIdx.x;     // 0..147967
        if (j >= 147840) return;                     // 385*384
        int r = j / 384, o = j % 384;
        unsigned short v = 0;
        if (r < 384) {
            unsigned u = __float_as_uint(wq[o * 384 + r]);
            v = (unsigned short)((u + 0x7fffu + ((u >> 16) & 1u)) >> 16);  // rne bf16
        }
        ((unsigned short*)(ws + WQB_OFF))[j] = v;
    }
}

// ---------------- K0b: BN constants ----------------
__global__ void k0_consts(const float* __restrict__ qg, const float* __restrict__ qb,
                          const float* __restrict__ qm, const float* __restrict__ qv,
                          const float* __restrict__ pg, const float* __restrict__ pb,
                          const float* __restrict__ pm, const float* __restrict__ pv,
                          const float* __restrict__ bp, char* __restrict__ ws) {
    int i = threadIdx.x;                         // 384 threads
    float qi = qg[i] / sqrtf(qv[i] + EPS);
    ((float*)(ws + QINV_OFF))[i] = qi;
    ((float*)(ws + QOFF_OFF))[i] = qb[i] - qm[i] * qi;
    float pi = pg[i] / sqrtf(pv[i] + EPS);
    float po = pb[i] - pm[i] * pi;
    ((float*)(ws + PINV_OFF))[i] = pi;
    ((float*)(ws + POFF_OFF))[i] = po;
    ((float*)(ws + C0_OFF))[i] = bp[i] * pi + po;   // output value when GEMM2 input is all-zero
}

// ---------------- K1: shortcut LIF -> n-packed spike bitmasks ----------------
__global__ __launch_bounds__(256) void k1_lif(const float* __restrict__ x,
                                              unsigned long long* __restrict__ xm) {
    int wid  = (blockIdx.x * 256 + threadIdx.x) >> 6;   // 0..98303
    int lane = threadIdx.x & 63;
    int c = wid % 384;
    int g = (wid / 384) & 15;
    int b = wid / (384 * 16);
    const float* xp = x + (size_t)b * CN + (size_t)c * 1024 + g * 64 + lane;
    float v = 0.f;
    #pragma unroll
    for (int t = 0; t < 4; ++t) {
        float xv = xp[(size_t)t * BCN];
        float h = v + (xv - v) * 0.5f;                  // v + (x - v)/tau, tau = 2
        bool s = (h >= 1.0f);
        unsigned long long m = __ballot(s);
        v = s ? 0.f : h;
        if (lane == 0) xm[(((size_t)t * 16 + b) * 16 + g) * 384 + c] = m;
    }
}

// ---------------- K1b: 64x64 bit transpose: n-packed -> c-packed ----------------
__global__ __launch_bounds__(256) void k1b_transpose(const unsigned long long* __restrict__ xm,
                                                     unsigned long long* __restrict__ xmT) {
    int wid  = (blockIdx.x * 256 + threadIdx.x) >> 6;   // 0..6143
    int lane = threadIdx.x & 63;
    int cg = wid % 6;
    int g  = (wid / 6) % 16;
    int tb = wid / 96;                                  // t*16 + b
    unsigned long long W = xm[((size_t)tb * 16 + g) * 384 + cg * 64 + lane];
    unsigned long long T = 0ull;
    #pragma unroll
    for (int k = 0; k < 64; ++k) {
        unsigned long long bk = __ballot((W >> k) & 1ull);  // bit c = spike(c, n=g*64+k)
        if (lane == k) T = bk;
    }
    xmT[((size_t)tb * 1024 + g * 64 + lane) * 6 + cg] = T;
}

// ---------------- K1c: c-packed bitmasks -> padded u16 index lists ----------------
// thread = column (t,b,n). k<=LCAP: emit indices, pad last 8-batch with 384 (zero row),
// lcnt = ceil(k/8). k>LCAP: lcnt = 0xFF -> k2 uses bitmask fallback (any-input correct).
__global__ __launch_bounds__(256) void k1c_lists(const unsigned long long* __restrict__ xmT,
                                                 unsigned short* __restrict__ lists,
                                                 unsigned char* __restrict__ lcnt) {
    int col = blockIdx.x * 256 + threadIdx.x;           // 0..65535
    const unsigned long long* mp = xmT + (size_t)col * 6;
    unsigned short* lp = lists + (size_t)col * LCAP;
    int k = 0;
    #pragma unroll
    for (int cg = 0; cg < 6; ++cg) {
        unsigned long long m = mp[cg];
        while (m) {
            int j = __builtin_ctzll(m);
            m &= m - 1;
            if (k < LCAP) lp[k] = (unsigned short)(cg * 64 + j);
            ++k;
        }
    }
    if (k > LCAP) { lcnt[col] = 0xFF; return; }
    int r = (k + 7) >> 3;
    for (int i = k; i < r * 8; ++i) lp[i] = 384;        // pad to full 8-batch
    lcnt[col] = (unsigned char)r;
}

// ---------------- K2: list-driven gather GEMM1 + BN + q-LIF + attn mask ------------
// block = (b, 16-n tile); 384 threads; thread owns output channel o = tid.
// Per (nl,t): rounds of {16B index load -> 8 independent bf16 row loads -> 8 fadds}
// into 8 split accumulators; tree-reduce. No mask walking in the hot loop.
__global__ __launch_bounds__(384) void k2_qpath(const unsigned short* __restrict__ wqb,
                                                const float* __restrict__ qinv_,
                                                const float* __restrict__ qoff_,
                                                const unsigned short* __restrict__ lists,
                                                const unsigned char* __restrict__ lcnt,
                                                const unsigned long long* __restrict__ xmT,
                                                const unsigned char* __restrict__ ak,
                                                const unsigned char* __restrict__ av,
                                                unsigned long long* __restrict__ msT) {
    const int tid  = threadIdx.x;                // output channel o
    const int lane = tid & 63;
    const int wgrp = tid >> 6;                   // o-group 0..5
    const int nt   = blockIdx.x & 63;            // 16-wide n-tile
    const int b    = blockIdx.x >> 6;
    const float qi = qinv_[tid], qo = qoff_[tid];

    for (int nl = 0; nl < 16; ++nl) {
        const int n = nt * 16 + nl;
        float acc[4];
        #pragma unroll
        for (int t = 0; t < 4; ++t) {
            const int col = ((t * 16 + b) << 10) + n;
            const int rounds = lcnt[col];
            float a0=0.f,a1=0.f,a2=0.f,a3=0.f,a4=0.f,a5=0.f,a6=0.f,a7=0.f;
            if (rounds != 0xFF) {
                const unsigned short* lp = lists + (size_t)col * LCAP;
                for (int r = 0; r < rounds; ++r) {
                    const uint4 iw = *(const uint4*)(lp + r * 8);   // 8 u16 indices
                    const int i0 = iw.x & 0xffff, i1 = iw.x >> 16;
                    const int i2 = iw.y & 0xffff, i3 = iw.y >> 16;
                    const int i4 = iw.z & 0xffff, i5 = iw.z >> 16;
                    const int i6 = iw.w & 0xffff, i7 = iw.w >> 16;
                    const unsigned w0 = wqb[i0 * 384 + tid], w1 = wqb[i1 * 384 + tid];
                    const unsigned w2 = wqb[i2 * 384 + tid], w3 = wqb[i3 * 384 + tid];
                    const unsigned w4 = wqb[i4 * 384 + tid], w5 = wqb[i5 * 384 + tid];
                    const unsigned w6 = wqb[i6 * 384 + tid], w7 = wqb[i7 * 384 + tid];
                    a0 += __uint_as_float(w0 << 16); a1 += __uint_as_float(w1 << 16);
                    a2 += __uint_as_float(w2 << 16); a3 += __uint_as_float(w3 << 16);
                    a4 += __uint_as_float(w4 << 16); a5 += __uint_as_float(w5 << 16);
                    a6 += __uint_as_float(w6 << 16); a7 += __uint_as_float(w7 << 16);
                }
            } else {
                // overflow fallback: bitmask gather (correct for any input)
                const unsigned long long* mp = xmT + (size_t)col * 6;
                #pragma unroll
                for (int cg = 0; cg < 6; ++cg) {
                    unsigned long long mm = mp[cg];
                    while (mm) {
                        int j = __builtin_ctzll(mm);
                        mm &= mm - 1;
                        a0 += __uint_as_float((unsigned)wqb[(cg * 64 + j) * 384 + tid] << 16);
                    }
                }
            }
            acc[t] = ((a0 + a4) + (a1 + a5)) + ((a2 + a6) + (a3 + a7));
        }
        // BN + LIF + attn-mask epilogue
        float v = 0.f;
        #pragma unroll
        for (int t = 0; t < 4; ++t) {
            float qbn = acc[t] * qi + qo;
            float h = 0.5f * (v + qbn);          // v + (q - v)/2
            bool sp = (h >= 1.0f);
            v = sp ? 0.f : h;
            if (sp) {                             // rare: attn-mask lookup only on q-spike
                size_t ix = ((size_t)((t * 16 + b) * 384 + tid) << 10) + n;
                sp = (ak[ix] != 0) && (av[ix] != 0);
            }
            unsigned long long bw = __ballot(sp);
            if (lane == 0)
                msT[((size_t)(t * 16 + b) * 1024 + n) * 6 + wgrp] = bw;
        }
    }
}

// ---------------- K3: proj GEMM2 + bias + BN (gather-based, atomic-free) ----------
__global__ __launch_bounds__(384) void k3_proj(const float* __restrict__ wpT,
                                               const float* __restrict__ pinv_,
                                               const float* __restrict__ poff_,
                                               const float* __restrict__ bp,
                                               const float* __restrict__ c0,
                                               const unsigned long long* __restrict__ msT,
                                               float* __restrict__ out) {
    __shared__ unsigned int wflag[6];
    const int tid = threadIdx.x;
    const int bid = blockIdx.x;
    const int g = bid & 15, b = (bid >> 4) & 15, t = bid >> 8;
    const unsigned long long* mbase = msT + ((size_t)(t * 16 + b) * 1024 + g * 64) * 6;
    unsigned long long m = mbase[tid];           // 384 words: n-local = tid/6, cg = tid%6
    unsigned long long anyb = __ballot(m != 0ull);
    if ((tid & 63) == 0) wflag[tid >> 6] = (anyb != 0ull) ? 1u : 0u;
    __syncthreads();
    unsigned int any = wflag[0] | wflag[1] | wflag[2] | wflag[3] | wflag[4] | wflag[5];
    size_t obase = (size_t)(t * 16 + b) * 384;

    if (!any) {
        // all-zero GEMM2 input: out = bp*inv + off, coalesced float4 stores
        #pragma unroll
        for (int k = 0; k < 16; ++k) {
            int i = tid + k * 384;               // 6144 float4 units in the (384o x 64n) tile
            int o = i >> 4, n4 = i & 15;
            float vv = c0[o];
            float4* dst = (float4*)out + (obase + o) * 256 + g * 16 + n4;
            *dst = make_float4(vv, vv, vv, vv);
        }
        return;
    }
    // slow path (never taken on this input): per-n VGPR gather
    float pi = pinv_[tid], po = poff_[tid], bb = bp[tid];
    for (int nl = 0; nl < 64; ++nl) {
        float acc = 0.f;
        #pragma unroll
        for (int cg = 0; cg < 6; ++cg) {
            unsigned long long mm = mbase[nl * 6 + cg];
            while (mm) {
                int j = __builtin_ctzll(mm);
                mm &= mm - 1;
                acc += wpT[(size_t)(cg * 64 + j) * 384 + tid];
            }
        }
        out[(obase + tid) * 1024 + g * 64 + nl] = (acc + bb) * pi + po;
    }
}

extern "C" void kernel_launch(void* const* d_in, const int* in_sizes, int n_in,
                              void* d_out, int out_size, void* d_ws, size_t ws_size,
                              hipStream_t stream) {
    const float* x  = (const float*)d_in[0];
    const unsigned char* ak = (const unsigned char*)d_in[1];
    const unsigned char* av = (const unsigned char*)d_in[2];
    const float* wq = (const float*)d_in[3];
    const float* qg = (const float*)d_in[4];
    const float* qb = (const float*)d_in[5];
    const float* qm = (const float*)d_in[6];
    const float* qv = (const float*)d_in[7];
    const float* wp = (const float*)d_in[8];
    const float* bp = (const float*)d_in[9];
    const float* pg = (const float*)d_in[10];
    const float* pb = (const float*)d_in[11];
    const float* pm = (const float*)d_in[12];
    const float* pv = (const float*)d_in[13];
    char* ws = (char*)d_ws;
    float* out = (float*)d_out;

    hipLaunchKernelGGL(k0_transpose, dim3(1154), dim3(256), 0, stream, wq, wp, ws);
    hipLaunchKernelGGL(k0_consts, dim3(1), dim3(384), 0, stream,
                       qg, qb, qm, qv, pg, pb, pm, pv, bp, ws);
    hipLaunchKernelGGL(k1_lif, dim3(24576), dim3(256), 0, stream,
                       x, (unsigned long long*)(ws + XM_OFF));
    hipLaunchKernelGGL(k1b_transpose, dim3(1536), dim3(256), 0, stream,
                       (const unsigned long long*)(ws + XM_OFF),
                       (unsigned long long*)(ws + XMT_OFF));
    hipLaunchKernelGGL(k1c_lists, dim3(256), dim3(256), 0, stream,
                       (const unsigned long long*)(ws + XMT_OFF),
                       (unsigned short*)(ws + LISTS_OFF),
                       (unsigned char*)(ws + LCNT_OFF));
    hipLaunchKernelGGL(k2_qpath, dim3(1024), dim3(384), 0, stream,
                       (const unsigned short*)(ws + WQB_OFF),
                       (const float*)(ws + QINV_OFF), (const float*)(ws + QOFF_OFF),
                       (const unsigned short*)(ws + LISTS_OFF),
                       (const unsigned char*)(ws + LCNT_OFF),
                       (const unsigned long long*)(ws + XMT_OFF), ak, av,
                       (unsigned long long*)(ws + MST_OFF));
    hipLaunchKernelGGL(k3_proj, dim3(1024), dim3(384), 0, stream,
                       (const float*)(ws + WPT_OFF), (const float*)(ws + PINV_OFF),
                       (const float*)(ws + POFF_OFF), bp, (const float*)(ws + C0_OFF),
                       (const unsigned long long*)(ws + MST_OFF), out);
}

// Round 6
// 141.802 us; speedup vs baseline: 1.7940x; 1.0022x over previous
//
#include <hip/hip_runtime.h>
#include <cstdint>

#define CN (384*1024)          // 393216
#define BCN (16*CN)            // 6291456
#define EPS 1e-5f
#define LCAP 24                // index-list capacity per (t,b,n) column

// workspace layout (bytes)
#define WPT_OFF   0u           // f32[384][384] = 589824
#define WQB_OFF   589824u      // bf16-as-u16[385][384] = 295680 (row 384 = zeros), ends 885504
#define QINV_OFF  1179648u
#define QOFF_OFF  (QINV_OFF + 1536u)
#define PINV_OFF  (QINV_OFF + 3072u)
#define POFF_OFF  (QINV_OFF + 4608u)
#define C0_OFF    (QINV_OFF + 6144u)
#define LCNT_OFF  1187840u     // u8[65536], ends 1253376
#define LISTS_OFF 2097152u     // u16[65536][24] = 3145728, ends 5242880
#define XMT_OFF   5242880u     // u64[4][16][1024][6] c-packed spikes, ends 8388608
#define XM_OFF    8388608u     // u64[4][16][16][384] n-packed spikes, ends 11534336
#define MST_OFF   XM_OFF       // masked q-spikes, c-packed; reuses xm (dead after k1b)

// ---------------- K0a: transposes: wp -> f32 wpT, wq -> bf16 wqb (+ zero row) ------
__global__ __launch_bounds__(256) void k0_transpose(const float* __restrict__ wq,
                                                    const float* __restrict__ wp,
                                                    char* __restrict__ ws) {
    int bid = blockIdx.x;
    if (bid < 576) {
        int i = bid * 256 + threadIdx.x;             // 0..147455
        int c = i / 384, o = i % 384;
        ((float*)(ws + WPT_OFF))[c * 384 + o] = wp[o * 384 + c];
    } else {
        int j = (bid - 576) * 256 + threadIdx.x;     // 0..147967
        if (j >= 147840) return;                     // 385*384
        int r = j / 384, o = j % 384;
        unsigned short v = 0;
        if (r < 384) {
            unsigned u = __float_as_uint(wq[o * 384 + r]);
            v = (unsigned short)((u + 0x7fffu + ((u >> 16) & 1u)) >> 16);  // rne bf16
        }
        ((unsigned short*)(ws + WQB_OFF))[j] = v;
    }
}

// ---------------- K0b: BN constants ----------------
__global__ void k0_consts(const float* __restrict__ qg, const float* __restrict__ qb,
                          const float* __restrict__ qm, const float* __restrict__ qv,
                          const float* __restrict__ pg, const float* __restrict__ pb,
                          const float* __restrict__ pm, const float* __restrict__ pv,
                          const float* __restrict__ bp, char* __restrict__ ws) {
    int i = threadIdx.x;                         // 384 threads
    float qi = qg[i] / sqrtf(qv[i] + EPS);
    ((float*)(ws + QINV_OFF))[i] = qi;
    ((float*)(ws + QOFF_OFF))[i] = qb[i] - qm[i] * qi;
    float pi = pg[i] / sqrtf(pv[i] + EPS);
    float po = pb[i] - pm[i] * pi;
    ((float*)(ws + PINV_OFF))[i] = pi;
    ((float*)(ws + POFF_OFF))[i] = po;
    ((float*)(ws + C0_OFF))[i] = bp[i] * pi + po;   // output value when GEMM2 input is all-zero
}

// ---------------- K1: shortcut LIF -> n-packed spike bitmasks ----------------
__global__ __launch_bounds__(256) void k1_lif(const float* __restrict__ x,
                                              unsigned long long* __restrict__ xm) {
    int wid  = (blockIdx.x * 256 + threadIdx.x) >> 6;   // 0..98303
    int lane = threadIdx.x & 63;
    int c = wid % 384;
    int g = (wid / 384) & 15;
    int b = wid / (384 * 16);
    const float* xp = x + (size_t)b * CN + (size_t)c * 1024 + g * 64 + lane;
    float v = 0.f;
    #pragma unroll
    for (int t = 0; t < 4; ++t) {
        float xv = xp[(size_t)t * BCN];
        float h = v + (xv - v) * 0.5f;                  // v + (x - v)/tau, tau = 2
        bool s = (h >= 1.0f);
        unsigned long long m = __ballot(s);
        v = s ? 0.f : h;
        if (lane == 0) xm[(((size_t)t * 16 + b) * 16 + g) * 384 + c] = m;
    }
}

// ---------------- K1b: 64x64 bit transpose: n-packed -> c-packed ----------------
__global__ __launch_bounds__(256) void k1b_transpose(const unsigned long long* __restrict__ xm,
                                                     unsigned long long* __restrict__ xmT) {
    int wid  = (blockIdx.x * 256 + threadIdx.x) >> 6;   // 0..6143
    int lane = threadIdx.x & 63;
    int cg = wid % 6;
    int g  = (wid / 6) % 16;
    int tb = wid / 96;                                  // t*16 + b
    unsigned long long W = xm[((size_t)tb * 16 + g) * 384 + cg * 64 + lane];
    unsigned long long T = 0ull;
    #pragma unroll
    for (int k = 0; k < 64; ++k) {
        unsigned long long bk = __ballot((W >> k) & 1ull);  // bit c = spike(c, n=g*64+k)
        if (lane == k) T = bk;
    }
    xmT[((size_t)tb * 1024 + g * 64 + lane) * 6 + cg] = T;
}

// ---------------- K1c: c-packed bitmasks -> padded u16 index lists ----------------
// thread = column (t,b,n). k<=LCAP: emit indices, pad last 8-batch with 384 (zero row),
// lcnt = ceil(k/8). k>LCAP: lcnt = 0xFF -> k2 uses bitmask fallback (any-input correct).
__global__ __launch_bounds__(256) void k1c_lists(const unsigned long long* __restrict__ xmT,
                                                 unsigned short* __restrict__ lists,
                                                 unsigned char* __restrict__ lcnt) {
    int col = blockIdx.x * 256 + threadIdx.x;           // 0..65535
    const unsigned long long* mp = xmT + (size_t)col * 6;
    unsigned short* lp = lists + (size_t)col * LCAP;
    int k = 0;
    #pragma unroll
    for (int cg = 0; cg < 6; ++cg) {
        unsigned long long m = mp[cg];
        while (m) {
            int j = __builtin_ctzll(m);
            m &= m - 1;
            if (k < LCAP) lp[k] = (unsigned short)(cg * 64 + j);
            ++k;
        }
    }
    if (k > LCAP) { lcnt[col] = 0xFF; return; }
    int r = (k + 7) >> 3;
    for (int i = k; i < r * 8; ++i) lp[i] = 384;        // pad to full 8-batch
    lcnt[col] = (unsigned char)r;
}

// ---------------- K2: scalar-indexed gather GEMM1 + BN + q-LIF + attn mask ---------
// block = (b, 16-n tile); 384 threads; thread owns output channel o = tid.
// Indices/counters are block-uniform -> readfirstlane forces them into SGPRs; weight
// loads become saddr-form (scalar base + tid*2 offset): 3 VALU per gathered weight.
__global__ __launch_bounds__(384) void k2_qpath(const unsigned short* __restrict__ wqb,
                                                const float* __restrict__ qinv_,
                                                const float* __restrict__ qoff_,
                                                const unsigned short* __restrict__ lists,
                                                const unsigned char* __restrict__ lcnt,
                                                const unsigned long long* __restrict__ xmT,
                                                const unsigned char* __restrict__ ak,
                                                const unsigned char* __restrict__ av,
                                                unsigned long long* __restrict__ msT) {
    const int tid  = threadIdx.x;                // output channel o
    const int lane = tid & 63;
    const int wgrp = tid >> 6;                   // o-group 0..5
    const int nt   = blockIdx.x & 63;            // 16-wide n-tile
    const int b    = blockIdx.x >> 6;
    const float qi = qinv_[tid], qo = qoff_[tid];

    for (int nl = 0; nl < 16; ++nl) {
        const int n = nt * 16 + nl;
        float acc[4];
        #pragma unroll
        for (int t = 0; t < 4; ++t) {
            const int col = ((t * 16 + b) << 10) + n;            // block-uniform
            const int rounds = __builtin_amdgcn_readfirstlane(lcnt[col]);
            float a0=0.f,a1=0.f,a2=0.f,a3=0.f,a4=0.f,a5=0.f,a6=0.f,a7=0.f;
            if (rounds != 0xFF) {
                const unsigned short* lp = lists + (size_t)col * LCAP;
                for (int r = 0; r < rounds; ++r) {
                    const uint4 iw = *(const uint4*)(lp + r * 8);     // uniform addr
                    const int i0 = __builtin_amdgcn_readfirstlane((int)(iw.x & 0xffffu));
                    const int i1 = __builtin_amdgcn_readfirstlane((int)(iw.x >> 16));
                    const int i2 = __builtin_amdgcn_readfirstlane((int)(iw.y & 0xffffu));
                    const int i3 = __builtin_amdgcn_readfirstlane((int)(iw.y >> 16));
                    const int i4 = __builtin_amdgcn_readfirstlane((int)(iw.z & 0xffffu));
                    const int i5 = __builtin_amdgcn_readfirstlane((int)(iw.z >> 16));
                    const int i6 = __builtin_amdgcn_readfirstlane((int)(iw.w & 0xffffu));
                    const int i7 = __builtin_amdgcn_readfirstlane((int)(iw.w >> 16));
                    const unsigned w0 = wqb[i0 * 384 + tid], w1 = wqb[i1 * 384 + tid];
                    const unsigned w2 = wqb[i2 * 384 + tid], w3 = wqb[i3 * 384 + tid];
                    const unsigned w4 = wqb[i4 * 384 + tid], w5 = wqb[i5 * 384 + tid];
                    const unsigned w6 = wqb[i6 * 384 + tid], w7 = wqb[i7 * 384 + tid];
                    a0 += __uint_as_float(w0 << 16); a1 += __uint_as_float(w1 << 16);
                    a2 += __uint_as_float(w2 << 16); a3 += __uint_as_float(w3 << 16);
                    a4 += __uint_as_float(w4 << 16); a5 += __uint_as_float(w5 << 16);
                    a6 += __uint_as_float(w6 << 16); a7 += __uint_as_float(w7 << 16);
                }
            } else {
                // overflow fallback: bitmask gather (correct for any input)
                const unsigned long long* mp = xmT + (size_t)col * 6;
                #pragma unroll
                for (int cg = 0; cg < 6; ++cg) {
                    unsigned long long mm = mp[cg];
                    while (mm) {
                        int j = __builtin_ctzll(mm);
                        mm &= mm - 1;
                        a0 += __uint_as_float((unsigned)wqb[(cg * 64 + j) * 384 + tid] << 16);
                    }
                }
            }
            acc[t] = ((a0 + a4) + (a1 + a5)) + ((a2 + a6) + (a3 + a7));
        }
        // BN + LIF + attn-mask epilogue
        float v = 0.f;
        #pragma unroll
        for (int t = 0; t < 4; ++t) {
            float qbn = acc[t] * qi + qo;
            float h = 0.5f * (v + qbn);          // v + (q - v)/2
            bool sp = (h >= 1.0f);
            v = sp ? 0.f : h;
            if (sp) {                             // rare: attn-mask lookup only on q-spike
                size_t ix = ((size_t)((t * 16 + b) * 384 + tid) << 10) + n;
                sp = (ak[ix] != 0) && (av[ix] != 0);
            }
            unsigned long long bw = __ballot(sp);
            if (lane == 0)
                msT[((size_t)(t * 16 + b) * 1024 + n) * 6 + wgrp] = bw;
        }
    }
}

// ---------------- K3: proj GEMM2 + bias + BN (gather-based, atomic-free) ----------
__global__ __launch_bounds__(384) void k3_proj(const float* __restrict__ wpT,
                                               const float* __restrict__ pinv_,
                                               const float* __restrict__ poff_,
                                               const float* __restrict__ bp,
                                               const float* __restrict__ c0,
                                               const unsigned long long* __restrict__ msT,
                                               float* __restrict__ out) {
    __shared__ unsigned int wflag[6];
    const int tid = threadIdx.x;
    const int bid = blockIdx.x;
    const int g = bid & 15, b = (bid >> 4) & 15, t = bid >> 8;
    const unsigned long long* mbase = msT + ((size_t)(t * 16 + b) * 1024 + g * 64) * 6;
    unsigned long long m = mbase[tid];           // 384 words: n-local = tid/6, cg = tid%6
    unsigned long long anyb = __ballot(m != 0ull);
    if ((tid & 63) == 0) wflag[tid >> 6] = (anyb != 0ull) ? 1u : 0u;
    __syncthreads();
    unsigned int any = wflag[0] | wflag[1] | wflag[2] | wflag[3] | wflag[4] | wflag[5];
    size_t obase = (size_t)(t * 16 + b) * 384;

    if (!any) {
        // all-zero GEMM2 input: out = bp*inv + off, coalesced float4 stores
        #pragma unroll
        for (int k = 0; k < 16; ++k) {
            int i = tid + k * 384;               // 6144 float4 units in the (384o x 64n) tile
            int o = i >> 4, n4 = i & 15;
            float vv = c0[o];
            float4* dst = (float4*)out + (obase + o) * 256 + g * 16 + n4;
            *dst = make_float4(vv, vv, vv, vv);
        }
        return;
    }
    // slow path (never taken on this input): per-n VGPR gather
    float pi = pinv_[tid], po = poff_[tid], bb = bp[tid];
    for (int nl = 0; nl < 64; ++nl) {
        float acc = 0.f;
        #pragma unroll
        for (int cg = 0; cg < 6; ++cg) {
            unsigned long long mm = mbase[nl * 6 + cg];
            while (mm) {
                int j = __builtin_ctzll(mm);
                mm &= mm - 1;
                acc += wpT[(size_t)(cg * 64 + j) * 384 + tid];
            }
        }
        out[(obase + tid) * 1024 + g * 64 + nl] = (acc + bb) * pi + po;
    }
}

extern "C" void kernel_launch(void* const* d_in, const int* in_sizes, int n_in,
                              void* d_out, int out_size, void* d_ws, size_t ws_size,
                              hipStream_t stream) {
    const float* x  = (const float*)d_in[0];
    const unsigned char* ak = (const unsigned char*)d_in[1];
    const unsigned char* av = (const unsigned char*)d_in[2];
    const float* wq = (const float*)d_in[3];
    const float* qg = (const float*)d_in[4];
    const float* qb = (const float*)d_in[5];
    const float* qm = (const float*)d_in[6];
    const float* qv = (const float*)d_in[7];
    const float* wp = (const float*)d_in[8];
    const float* bp = (const float*)d_in[9];
    const float* pg = (const float*)d_in[10];
    const float* pb = (const float*)d_in[11];
    const float* pm = (const float*)d_in[12];
    const float* pv = (const float*)d_in[13];
    char* ws = (char*)d_ws;
    float* out = (float*)d_out;

    hipLaunchKernelGGL(k0_transpose, dim3(1154), dim3(256), 0, stream, wq, wp, ws);
    hipLaunchKernelGGL(k0_consts, dim3(1), dim3(384), 0, stream,
                       qg, qb, qm, qv, pg, pb, pm, pv, bp, ws);
    hipLaunchKernelGGL(k1_lif, dim3(24576), dim3(256), 0, stream,
                       x, (unsigned long long*)(ws + XM_OFF));
    hipLaunchKernelGGL(k1b_transpose, dim3(1536), dim3(256), 0, stream,
                       (const unsigned long long*)(ws + XM_OFF),
                       (unsigned long long*)(ws + XMT_OFF));
    hipLaunchKernelGGL(k1c_lists, dim3(256), dim3(256), 0, stream,
                       (const unsigned long long*)(ws + XMT_OFF),
                       (unsigned short*)(ws + LISTS_OFF),
                       (unsigned char*)(ws + LCNT_OFF));
    hipLaunchKernelGGL(k2_qpath, dim3(1024), dim3(384), 0, stream,
                       (const unsigned short*)(ws + WQB_OFF),
                       (const float*)(ws + QINV_OFF), (const float*)(ws + QOFF_OFF),
                       (const unsigned short*)(ws + LISTS_OFF),
                       (const unsigned char*)(ws + LCNT_OFF),
                       (const unsigned long long*)(ws + XMT_OFF), ak, av,
                       (unsigned long long*)(ws + MST_OFF));
    hipLaunchKernelGGL(k3_proj, dim3(1024), dim3(384), 0, stream,
                       (const float*)(ws + WPT_OFF), (const float*)(ws + PINV_OFF),
                       (const float*)(ws + POFF_OFF), bp, (const float*)(ws + C0_OFF),
                       (const unsigned long long*)(ws + MST_OFF), out);
}